// Round 1
// baseline (445.273 us; speedup 1.0000x reference)
//
#include <hip/hip_runtime.h>
#include <hip/hip_bf16.h>
#include <math.h>

// Problem constants
#define BB 64
#define TT 4096
#define DD 256
#define UU 256
#define CHUNKS 8          // chunks per batch -> grid 512 blocks
#define TCHUNK 512        // TT / CHUNKS
#define MT 64             // timestep tile per iteration
#define NTILES 8          // TCHUNK / MT
#define LDA 264           // padded LDS row stride in bf16 elems (+8 pad)

typedef __attribute__((ext_vector_type(8))) short bf16x8;
typedef __attribute__((ext_vector_type(4))) float f32x4;

static __device__ __forceinline__ short f2bf(float f){
  unsigned u = __float_as_uint(f);
  u = (u + 0x7fffu + ((u >> 16) & 1u)) >> 16;   // RNE
  return (short)u;
}

// Kernel 0: W[d][u] fp32 -> Wt[u][d] bf16 (B-operand friendly layout)
__global__ void wconv_kernel(const float* __restrict__ W, short* __restrict__ Wt){
  int u = blockIdx.x;
  int d = threadIdx.x;
  Wt[u*DD + d] = f2bf(W[d*UU + u]);   // writes coalesced; reads L2-absorbed (W is 256 KB)
}

// Kernel 1: flash-style fused logits + online softmax + weighted sum (per chunk)
__global__ __launch_bounds__(256)
void attn_main_kernel(const float* __restrict__ X, const short* __restrict__ Wt,
                      const float* __restrict__ Wb, const float* __restrict__ Vw,
                      float* __restrict__ m_part, float* __restrict__ l_part,
                      float* __restrict__ ctx_part)
{
  __shared__ short a_tile[MT*LDA];   // 33792 B bf16 X tile
  __shared__ float s_logits[MT];
  __shared__ float s_p[MT];
  __shared__ float s_m, s_l, s_alpha;

  const int tid  = threadIdx.x;
  const int lane = tid & 63;
  const int wv   = tid >> 6;          // 4 waves, each owns 64 units
  const int b    = blockIdx.x >> 3;
  const int cchunk = blockIdx.x & 7;
  const int lo   = lane & 15;
  const int quad = lane >> 4;
  const int u_base = wv*64 + lo;

  if (tid == 0){ s_m = -INFINITY; s_l = 0.f; }

  float wb_r[4], v_r[4];
  #pragma unroll
  for (int nf=0; nf<4; ++nf){
    wb_r[nf] = Wb[u_base + nf*16];
    v_r[nf]  = Vw[u_base + nf*16];
  }

  float ctx = 0.f;
  const size_t x_chunk = ((size_t)b*TT + (size_t)cchunk*TCHUNK) * DD;

  for (int tile=0; tile<NTILES; ++tile){
    const int t0 = tile*MT;

    // ---- stage: 64x256 fp32 -> bf16 LDS tile ----
    if (tid < MT) s_logits[tid] = 0.f;
    #pragma unroll
    for (int p8=0; p8<8; ++p8){
      int e   = p8*256 + tid;        // 8-float unit index, coalesced across lanes
      int row = e >> 5;              // 32 units per row
      int col = (e & 31) * 8;
      const float4* src = reinterpret_cast<const float4*>(
          X + x_chunk + (size_t)(t0+row)*DD + col);
      float4 x0 = src[0];
      float4 x1 = src[1];
      bf16x8 v;
      v[0]=f2bf(x0.x); v[1]=f2bf(x0.y); v[2]=f2bf(x0.z); v[3]=f2bf(x0.w);
      v[4]=f2bf(x1.x); v[5]=f2bf(x1.y); v[6]=f2bf(x1.z); v[7]=f2bf(x1.w);
      *reinterpret_cast<bf16x8*>(&a_tile[row*LDA + col]) = v;
    }
    __syncthreads();

    // ---- MFMA: score[64 x 64units] per wave, K=256 ----
    f32x4 acc[4][4];
    #pragma unroll
    for (int mf=0; mf<4; ++mf)
      #pragma unroll
      for (int nf=0; nf<4; ++nf)
        acc[mf][nf] = (f32x4){0.f,0.f,0.f,0.f};

    #pragma unroll
    for (int kt=0; kt<8; ++kt){
      const int k0 = kt*32 + quad*8;
      bf16x8 af[4];
      #pragma unroll
      for (int mf=0; mf<4; ++mf)
        af[mf] = *reinterpret_cast<const bf16x8*>(&a_tile[(mf*16 + lo)*LDA + k0]);
      #pragma unroll
      for (int nf=0; nf<4; ++nf){
        bf16x8 bfv = *reinterpret_cast<const bf16x8*>(&Wt[(size_t)(u_base + nf*16)*DD + k0]);
        #pragma unroll
        for (int mf=0; mf<4; ++mf)
          acc[mf][nf] = __builtin_amdgcn_mfma_f32_16x16x32_bf16(af[mf], bfv, acc[mf][nf], 0, 0, 0);
      }
    }

    // ---- epilogue: tanh, dot with V, reduce over units ----
    // C/D layout: col(u)=lane&15, row(t)=quad*4+reg
    #pragma unroll
    for (int mf=0; mf<4; ++mf){
      #pragma unroll
      for (int r=0; r<4; ++r){
        float part = 0.f;
        #pragma unroll
        for (int nf=0; nf<4; ++nf){
          float s  = acc[mf][nf][r] + wb_r[nf];
          float e2 = __expf(2.f*s);
          float th = 1.f - 2.f/(e2 + 1.f);     // robust tanh: saturates at +/-1
          part = fmaf(th, v_r[nf], part);
        }
        part += __shfl_xor(part, 1);
        part += __shfl_xor(part, 2);
        part += __shfl_xor(part, 4);
        part += __shfl_xor(part, 8);
        if (lo == 0) atomicAdd(&s_logits[mf*16 + quad*4 + r], part);
      }
    }
    __syncthreads();

    // ---- online softmax update (wave 0 handles the 64 tile logits) ----
    if (tid < MT){
      float lt = s_logits[tid];
      float mx = lt;
      #pragma unroll
      for (int o=32; o; o>>=1) mx = fmaxf(mx, __shfl_xor(mx, o));
      float m_old = s_m;
      float m_new = fmaxf(m_old, mx);
      float p = __expf(lt - m_new);
      s_p[tid] = p;
      float sum = p;
      #pragma unroll
      for (int o=32; o; o>>=1) sum += __shfl_xor(sum, o);
      if (tid == 0){
        float alpha = __expf(m_old - m_new);   // exp(-inf)=0 handles first tile
        s_alpha = alpha;
        s_l = s_l * alpha + sum;
        s_m = m_new;
      }
    }
    __syncthreads();

    // ---- ctx update: thread d accumulates sum_t p[t] * X[t][d] (fp32, L2 re-read) ----
    float alpha = s_alpha;
    ctx *= alpha;
    const float* xcol = X + x_chunk + (size_t)t0*DD + tid;
    #pragma unroll
    for (int t2=0; t2<MT; ++t2)
      ctx = fmaf(s_p[t2], xcol[(size_t)t2*DD], ctx);
  }

  __syncthreads();
  const int pidx = b*CHUNKS + cchunk;
  if (tid == 0){ m_part[pidx] = s_m; l_part[pidx] = s_l; }
  ctx_part[(size_t)pidx*DD + tid] = ctx;
}

// Kernel 2: merge chunk partials per batch
__global__ void merge_kernel(const float* __restrict__ m_part, const float* __restrict__ l_part,
                             const float* __restrict__ ctx_part, float* __restrict__ out)
{
  int b = blockIdx.x;
  int d = threadIdx.x;
  float mg = -INFINITY;
  #pragma unroll
  for (int c=0; c<CHUNKS; ++c) mg = fmaxf(mg, m_part[b*CHUNKS+c]);
  float lg = 0.f, s = 0.f;
  #pragma unroll
  for (int c=0; c<CHUNKS; ++c){
    float w = __expf(m_part[b*CHUNKS+c] - mg);
    lg += l_part[b*CHUNKS+c] * w;
    s  += ctx_part[(size_t)(b*CHUNKS+c)*DD + d] * w;
  }
  out[b*DD + d] = s / lg;
}

extern "C" void kernel_launch(void* const* d_in, const int* in_sizes, int n_in,
                              void* d_out, int out_size, void* d_ws, size_t ws_size,
                              hipStream_t stream)
{
  const float* X  = (const float*)d_in[0];
  const float* Ww = (const float*)d_in[1];
  const float* Wb = (const float*)d_in[2];
  const float* Vw = (const float*)d_in[3];
  // V_b (d_in[4]) shifts all logits equally -> cancels in softmax; ignored.
  float* out = (float*)d_out;

  // workspace layout: Wt bf16 (128 KB) | m (512 f) | l (512 f) | ctx (512*256 f)
  short* Wt     = (short*)d_ws;
  float* m_part = (float*)((char*)d_ws + (size_t)UU*DD*sizeof(short));
  float* l_part = m_part + BB*CHUNKS;
  float* ctx_part = l_part + BB*CHUNKS;

  wconv_kernel<<<UU, DD, 0, stream>>>(Ww, Wt);
  attn_main_kernel<<<BB*CHUNKS, 256, 0, stream>>>(X, Wt, Wb, Vw, m_part, l_part, ctx_part);
  merge_kernel<<<BB, DD, 0, stream>>>(m_part, l_part, ctx_part, out);
}